// Round 6
// baseline (81.220 us; speedup 1.0000x reference)
//
#include <hip/hip_runtime.h>
#include <math.h>

typedef __bf16 bf16;
typedef __bf16 bf16x4 __attribute__((ext_vector_type(4)));
typedef __bf16 bf16x8 __attribute__((ext_vector_type(8)));
typedef float f32x4 __attribute__((ext_vector_type(4)));

#define MFMA16(a,b,c) __builtin_amdgcn_mfma_f32_16x16x32_bf16((a),(b),(c),0,0,0)

static constexpr int HS  = 64;    // head size
static constexpr int SEQ = 2048;  // sequence length
static constexpr int NE  = 1024;  // n_embed
static constexpr int NB  = 8;     // batch

__device__ __forceinline__ bf16x8 cvt8(float4 a, float4 b) {
  bf16x8 r;
  r[0]=(bf16)a.x; r[1]=(bf16)a.y; r[2]=(bf16)a.z; r[3]=(bf16)a.w;
  r[4]=(bf16)b.x; r[5]=(bf16)b.y; r[6]=(bf16)b.z; r[7]=(bf16)b.w;
  return r;
}

// async global->LDS, 16 bytes per lane (lds dest = wave-uniform base + lane*16)
__device__ __forceinline__ void gload16(const void* g, void* l) {
  __builtin_amdgcn_global_load_lds(
      (const __attribute__((address_space(1))) void*)g,
      (__attribute__((address_space(3))) void*)l, 16, 0, 0);
}

// ---- W f32 -> bf16 (Wq pre-scaled by 1/sqrt(64)) ----
__global__ __launch_bounds__(256) void wcvt_kernel(
    const float* __restrict__ Wq, const float* __restrict__ Wk,
    const float* __restrict__ Wv, bf16* __restrict__ wqb,
    bf16* __restrict__ wkb, bf16* __restrict__ wvb)
{
  int i = (blockIdx.x * 256 + threadIdx.x) * 4;   // 64 blocks -> 65536 elems
  float4 q = *(const float4*)(Wq + i);
  float4 k = *(const float4*)(Wk + i);
  float4 v = *(const float4*)(Wv + i);
  bf16x4 qo, ko, vo;
  qo[0]=(bf16)(q.x*0.125f); qo[1]=(bf16)(q.y*0.125f); qo[2]=(bf16)(q.z*0.125f); qo[3]=(bf16)(q.w*0.125f);
  ko[0]=(bf16)k.x; ko[1]=(bf16)k.y; ko[2]=(bf16)k.z; ko[3]=(bf16)k.w;
  vo[0]=(bf16)v.x; vo[1]=(bf16)v.y; vo[2]=(bf16)v.z; vo[3]=(bf16)v.w;
  *(bf16x4*)(wqb + i) = qo;
  *(bf16x4*)(wkb + i) = ko;
  *(bf16x4*)(wvb + i) = vo;
}

// ---- projection: global_load_lds staging, XOR-swizzled linear LDS ----
// grid 512 x 256thr (4 waves). Blocks 0..255: Q from index; 256..511: K+V.
// LDS: Xs f32 [2][64 rows][16 segs of 16B] (seg' = seg ^ (row&15)),
//      Ws bf16 [2][64 rows][8 segs of 16B]  (seg' = seg ^ (row&7)).
// Per K-step: issue 6-8 global_load_lds, compute prev buffer, one barrier.
template<int KV>
__device__ __forceinline__ void proj_body(
    const float* __restrict__ X, const bf16* __restrict__ W0,
    const bf16* __restrict__ W1, bf16* __restrict__ out0,
    bf16* __restrict__ outVT, int slab, char* smem)
{
  const int tid  = threadIdx.x;
  const int lane = tid & 63;
  const int w    = tid >> 6;
  const int m    = lane & 15;
  const int g    = lane >> 4;
  const int rowBase = slab * 64;

  char* Xb  = smem;              // [2][16384]  X tile f32
  char* W0b = smem + 32768;      // [2][8192]   W0 tile bf16
  char* W1b = smem + 49152;      // [2][8192]   W1 tile bf16 (KV only)

  const f32x4 vz = {0.f,0.f,0.f,0.f};
  f32x4 accA[4] = {vz, vz, vz, vz};
  f32x4 accB[4] = {vz, vz, vz, vz};   // DCE'd when !KV

  const float* Xbase = X + (size_t)rowBase * NE;

  auto stage = [&](int kt, int buf) {
    // X: 4 instrs/thread; instr q covers rows (q*4+w)*4 .. +3 (1024B each)
#pragma unroll
    for (int q = 0; q < 4; ++q) {
      int r = (q*4 + w)*4 + (lane >> 4);
      int s = lane & 15;
      const float* src = Xbase + (size_t)r * NE + kt*64 + ((s ^ (r & 15)) * 4);
      void* dst = Xb + buf*16384 + (q*4 + w)*1024;      // wave-uniform base
      gload16(src, dst);
    }
    // W: 2 instrs/thread; instr q covers rows (q*4+w)*8 .. +7
#pragma unroll
    for (int q = 0; q < 2; ++q) {
      int r = (q*4 + w)*8 + (lane >> 3);
      int s = lane & 7;
      size_t soff = (size_t)r * NE + kt*64 + ((s ^ (r & 7)) * 8);
      void* dst0 = W0b + buf*8192 + (q*4 + w)*1024;
      gload16(W0 + soff, dst0);
      if (KV) {
        void* dst1 = W1b + buf*8192 + (q*4 + w)*1024;
        gload16(W1 + soff, dst1);
      }
    }
  };

  auto compute = [&](int buf) {
#pragma unroll
    for (int kk = 0; kk < 2; ++kk) {
      const int arow = 16*w + m;
      const int s0 = 2*(kk*4 + g);
      const char* ab = Xb + buf*16384 + arow*256;
      float4 x0 = *(const float4*)(ab + (( s0      ^ (arow & 15)) * 16));
      float4 x1 = *(const float4*)(ab + (((s0 + 1) ^ (arow & 15)) * 16));
      bf16x8 af = cvt8(x0, x1);
#pragma unroll
      for (int n = 0; n < 4; ++n) {
        const int col = 16*n + m;
        const int ws  = kk*4 + g;
        bf16x8 b0 = *(const bf16x8*)(W0b + buf*8192 + col*128 + ((ws ^ (col & 7)) * 16));
        accA[n] = MFMA16(af, b0, accA[n]);
        if (KV) {
          bf16x8 b1 = *(const bf16x8*)(W1b + buf*8192 + col*128 + ((ws ^ (col & 7)) * 16));
          accB[n] = MFMA16(af, b1, accB[n]);
        }
      }
    }
  };

  stage(0, 0);
  __syncthreads();            // drains stage-0 (vmcnt 0 implied)
  int buf = 0;
  for (int kt = 0; kt < 16; ++kt) {
    if (kt + 1 < 16) stage(kt + 1, buf ^ 1);   // async, no regs consumed
    compute(buf);
    __syncthreads();          // drains next-stage loads + guards LDS reuse
    buf ^= 1;
  }

  // C/D: col = lane&15, row = 4*(lane>>4)+i  [m89-verified]
#pragma unroll
  for (int n = 0; n < 4; ++n)
#pragma unroll
    for (int i = 0; i < 4; ++i) {
      int row = rowBase + 16*w + 4*g + i;
      int h   = 16*n + m;
      out0[(size_t)row * HS + h] = (bf16)accA[n][i];
      if (KV)
        outVT[((size_t)(row >> 11) * HS + h) * SEQ + (row & 2047)] =
            (bf16)accB[n][i];
    }
}

__global__ __launch_bounds__(256, 2) void proj_kernel(
    const float* __restrict__ index, const float* __restrict__ memory,
    const bf16* __restrict__ wqb, const bf16* __restrict__ wkb,
    const bf16* __restrict__ wvb, bf16* __restrict__ qb,
    bf16* __restrict__ kb, bf16* __restrict__ vtb)
{
  __shared__ __align__(1024) char smem[65536];   // 64 KB -> 2 blocks/CU
  if (blockIdx.x < 256)
    proj_body<0>(index,  wqb, nullptr, qb, nullptr, blockIdx.x, smem);
  else
    proj_body<1>(memory, wkb, wvb,     kb, vtb, blockIdx.x - 256, smem);
}

// ---- flash attention: wave-split kv, barrier-less main loop (unchanged R5) ----
__global__ __launch_bounds__(128, 2) void attn_kernel(
    const bf16* __restrict__ qb, const bf16* __restrict__ kb,
    const bf16* __restrict__ vtb, float* __restrict__ out)
{
  __shared__ __align__(16) bf16 Ks[2][64][72];    // per-wave K tile [kv][d]
  __shared__ __align__(16) bf16 VTs[2][64][72];   // per-wave V^T tile [d][kv]
  __shared__ __align__(16) bf16 Ps[2][16][72];    // per-wave P

  const int tid  = threadIdx.x;
  const int lane = tid & 63;
  const int w    = tid >> 6;
  const int m    = lane & 15;
  const int g    = lane >> 4;
  const int qt   = 127 - blockIdx.x;   // reversed: longest blocks first
  const int b    = blockIdx.y;
  const int nkv  = (qt >> 2) + 1;      // kv tiles of 64 covering rows <= qt*16+15
  const int r0   = lane >> 1;
  const int hh   = (lane & 1) * 32;

  bf16x8 qf0 = *(const bf16x8*)(qb + ((size_t)b*SEQ + qt*16 + m)*HS + g*8);
  bf16x8 qf1 = *(const bf16x8*)(qb + ((size_t)b*SEQ + qt*16 + m)*HS + 32 + g*8);

  const f32x4 vz = {0.f,0.f,0.f,0.f};
  f32x4 o_acc[4] = {vz, vz, vz, vz};
  float mrun[4], lrun[4];
#pragma unroll
  for (int i = 0; i < 4; ++i) { mrun[i] = -INFINITY; lrun[i] = 0.f; }

  bf16x8 kp[8], vp[8];
  const bf16* kbB = kb  + (size_t)b*SEQ*HS;
  const bf16* vtB = vtb + (size_t)b*HS*SEQ;

  auto loadKV = [&](int j) {
    const bf16* kt_ = kbB + (size_t)j*64*HS;
    const bf16* vt_ = vtB + j*64;
#pragma unroll
    for (int q = 0; q < 4; ++q) {
      kp[q]   = *(const bf16x8*)(kt_ + (size_t)r0*64        + hh + q*8);
      kp[4+q] = *(const bf16x8*)(kt_ + (size_t)(r0+32)*64   + hh + q*8);
      vp[q]   = *(const bf16x8*)(vt_ + (size_t)r0*SEQ       + hh + q*8);
      vp[4+q] = *(const bf16x8*)(vt_ + (size_t)(r0+32)*SEQ  + hh + q*8);
    }
  };
  auto writeKV = [&]() {
#pragma unroll
    for (int q = 0; q < 4; ++q) {
      *(bf16x8*)&Ks[w][r0][hh + q*8]      = kp[q];
      *(bf16x8*)&Ks[w][r0+32][hh + q*8]   = kp[4+q];
      *(bf16x8*)&VTs[w][r0][hh + q*8]     = vp[q];
      *(bf16x8*)&VTs[w][r0+32][hh + q*8]  = vp[4+q];
    }
  };

  int j = w;
  if (j < nkv) {
    loadKV(j);
    writeKV();
    while (true) {
      const int jn = j + 2;
      const bool more = jn < nkv;
      if (more) loadKV(jn);

      f32x4 s_acc[4];
#pragma unroll
      for (int n = 0; n < 4; ++n) {
        f32x4 z = vz;
        z = MFMA16(qf0, *(const bf16x8*)&Ks[w][16*n + m][g*8], z);
        z = MFMA16(qf1, *(const bf16x8*)&Ks[w][16*n + m][32 + g*8], z);
        s_acc[n] = z;
      }
      if (j == nkv - 1) {
#pragma unroll
        for (int n = 0; n < 4; ++n) {
          int gk = j*64 + 16*n + m;
#pragma unroll
          for (int i = 0; i < 4; ++i)
            if (gk > qt*16 + 4*g + i) s_acc[n][i] = -INFINITY;
        }
      }

      float corr[4], tsum[4];
#pragma unroll
      for (int i = 0; i < 4; ++i) {
        float mx = fmaxf(fmaxf(s_acc[0][i], s_acc[1][i]),
                         fmaxf(s_acc[2][i], s_acc[3][i]));
        mx = fmaxf(mx, __shfl_xor(mx, 1));
        mx = fmaxf(mx, __shfl_xor(mx, 2));
        mx = fmaxf(mx, __shfl_xor(mx, 4));
        mx = fmaxf(mx, __shfl_xor(mx, 8));
        float mnew = fmaxf(mrun[i], mx);
        corr[i] = __expf(mrun[i] - mnew);
        mrun[i] = mnew;
        tsum[i] = 0.f;
      }
#pragma unroll
      for (int n = 0; n < 4; ++n)
#pragma unroll
        for (int i = 0; i < 4; ++i) {
          float p = __expf(s_acc[n][i] - mrun[i]);
          tsum[i] += p;
          Ps[w][4*g + i][16*n + m] = (bf16)p;
        }
#pragma unroll
      for (int i = 0; i < 4; ++i) {
        float s = tsum[i];
        s += __shfl_xor(s, 1);
        s += __shfl_xor(s, 2);
        s += __shfl_xor(s, 4);
        s += __shfl_xor(s, 8);
        lrun[i] = lrun[i] * corr[i] + s;
      }
#pragma unroll
      for (int n = 0; n < 4; ++n)
#pragma unroll
        for (int i = 0; i < 4; ++i) o_acc[n][i] *= corr[i];

#pragma unroll
      for (int kk = 0; kk < 2; ++kk) {
        bf16x8 pf = *(const bf16x8*)&Ps[w][m][kk*32 + g*8];
#pragma unroll
        for (int n = 0; n < 4; ++n) {
          bf16x8 vf = *(const bf16x8*)&VTs[w][16*n + m][kk*32 + g*8];
          o_acc[n] = MFMA16(pf, vf, o_acc[n]);
        }
      }

      if (!more) break;
      writeKV();
      j = jn;
    }
  }

  // ---- cross-wave merge of the two online-softmax partials ----
  float* PO = (float*)&Ks[w][0][0];
  float* PM = (float*)&VTs[w][0][0];
#pragma unroll
  for (int n = 0; n < 4; ++n)
#pragma unroll
    for (int i = 0; i < 4; ++i)
      PO[(4*g + i)*64 + 16*n + m] = o_acc[n][i];
  if (m == 0) {
#pragma unroll
    for (int i = 0; i < 4; ++i) {
      PM[4*g + i]      = mrun[i];
      PM[16 + 4*g + i] = lrun[i];
    }
  }
  __syncthreads();

  {
    const int r  = tid >> 3;
    const int c0 = (tid & 7) * 8;
    const float* O0 = (const float*)&Ks[0][0][0];
    const float* O1 = (const float*)&Ks[1][0][0];
    const float* M0 = (const float*)&VTs[0][0][0];
    const float* M1 = (const float*)&VTs[1][0][0];
    float m0 = M0[r], l0 = M0[16 + r];
    float m1 = M1[r], l1 = M1[16 + r];
    float mx = fmaxf(m0, m1);
    float s0 = __expf(m0 - mx), s1 = __expf(m1 - mx);
    float inv = 1.f / (s0*l0 + s1*l1);
    float4 x0 = *(const float4*)(O0 + r*64 + c0);
    float4 x1 = *(const float4*)(O0 + r*64 + c0 + 4);
    float4 y0 = *(const float4*)(O1 + r*64 + c0);
    float4 y1 = *(const float4*)(O1 + r*64 + c0 + 4);
    float4 o0, o1;
    o0.x=(x0.x*s0+y0.x*s1)*inv; o0.y=(x0.y*s0+y0.y*s1)*inv;
    o0.z=(x0.z*s0+y0.z*s1)*inv; o0.w=(x0.w*s0+y0.w*s1)*inv;
    o1.x=(x1.x*s0+y1.x*s1)*inv; o1.y=(x1.y*s0+y1.y*s1)*inv;
    o1.z=(x1.z*s0+y1.z*s1)*inv; o1.w=(x1.w*s0+y1.w*s1)*inv;
    float* op = out + ((size_t)b*SEQ + qt*16 + r) * HS + c0;
    *(float4*)(op)     = o0;
    *(float4*)(op + 4) = o1;
  }
}

extern "C" void kernel_launch(void* const* d_in, const int* in_sizes, int n_in,
                              void* d_out, int out_size, void* d_ws, size_t ws_size,
                              hipStream_t stream) {
  (void)in_sizes; (void)n_in; (void)out_size; (void)ws_size;
  const float* index  = (const float*)d_in[0];
  const float* memory = (const float*)d_in[1];
  const float* Wq     = (const float*)d_in[2];
  const float* Wk     = (const float*)d_in[3];
  const float* Wv     = (const float*)d_in[4];
  float* out = (float*)d_out;

  bf16* qb  = (bf16*)d_ws;                          // [NB*SEQ][64]
  bf16* kb  = qb  + (size_t)NB * SEQ * HS;          // [NB*SEQ][64]
  bf16* vtb = kb  + (size_t)NB * SEQ * HS;          // [NB][64][SEQ]
  bf16* wqb = vtb + (size_t)NB * SEQ * HS;          // [64][1024] (pre-scaled)
  bf16* wkb = wqb + (size_t)HS * NE;
  bf16* wvb = wkb + (size_t)HS * NE;

  wcvt_kernel<<<dim3(64), 256, 0, stream>>>(Wq, Wk, Wv, wqb, wkb, wvb);
  proj_kernel<<<dim3(512), 256, 0, stream>>>(index, memory, wqb, wkb, wvb, qb, kb, vtb);
  attn_kernel<<<dim3(128, 8), 128, 0, stream>>>(qb, kb, vtb, out);
}

// Round 8
// 72.367 us; speedup vs baseline: 1.1223x; 1.1223x over previous
//
#include <hip/hip_runtime.h>
#include <math.h>

typedef __bf16 bf16;
typedef __bf16 bf16x4 __attribute__((ext_vector_type(4)));
typedef __bf16 bf16x8 __attribute__((ext_vector_type(8)));
typedef float f32x4 __attribute__((ext_vector_type(4)));

#define MFMA16(a,b,c) __builtin_amdgcn_mfma_f32_16x16x32_bf16((a),(b),(c),0,0,0)

static constexpr int HS  = 64;    // head size
static constexpr int SEQ = 2048;  // sequence length
static constexpr int NE  = 1024;  // n_embed
static constexpr int NB  = 8;     // batch

__device__ __forceinline__ bf16x8 cvt8(float4 a, float4 b) {
  bf16x8 r;
  r[0]=(bf16)a.x; r[1]=(bf16)a.y; r[2]=(bf16)a.z; r[3]=(bf16)a.w;
  r[4]=(bf16)b.x; r[5]=(bf16)b.y; r[6]=(bf16)b.z; r[7]=(bf16)b.w;
  return r;
}

// async global->LDS, 16 bytes per lane (lds dest = wave-uniform base + lane*16)
__device__ __forceinline__ void gload16(const void* g, void* l) {
  __builtin_amdgcn_global_load_lds(
      (const __attribute__((address_space(1))) void*)g,
      (__attribute__((address_space(3))) void*)l, 16, 0, 0);
}

// ---- W f32 -> bf16 (Wq pre-scaled by 1/sqrt(64)) ----
__global__ __launch_bounds__(256) void wcvt_kernel(
    const float* __restrict__ Wq, const float* __restrict__ Wk,
    const float* __restrict__ Wv, bf16* __restrict__ wqb,
    bf16* __restrict__ wkb, bf16* __restrict__ wvb)
{
  int i = (blockIdx.x * 256 + threadIdx.x) * 4;   // 64 blocks -> 65536 elems
  float4 q = *(const float4*)(Wq + i);
  float4 k = *(const float4*)(Wk + i);
  float4 v = *(const float4*)(Wv + i);
  bf16x4 qo, ko, vo;
  qo[0]=(bf16)(q.x*0.125f); qo[1]=(bf16)(q.y*0.125f); qo[2]=(bf16)(q.z*0.125f); qo[3]=(bf16)(q.w*0.125f);
  ko[0]=(bf16)k.x; ko[1]=(bf16)k.y; ko[2]=(bf16)k.z; ko[3]=(bf16)k.w;
  vo[0]=(bf16)v.x; vo[1]=(bf16)v.y; vo[2]=(bf16)v.z; vo[3]=(bf16)v.w;
  *(bf16x4*)(wqb + i) = qo;
  *(bf16x4*)(wkb + i) = ko;
  *(bf16x4*)(wvb + i) = vo;
}

// ---- projection: global_load_lds + 3-buffer counted-vmcnt pipeline ----
// grid 512 x 256thr (4 waves). Blocks 0..255: Q from index; 256..511: K+V.
// Per K-step t: wait vmcnt(L) [stage(t) done, t+1 in flight], raw s_barrier,
// issue stage(t+2) into buf (t+2)%3, compute buf t%3. Loads cross barriers.
template<int KV>
__device__ __forceinline__ void proj_body(
    const float* __restrict__ X, const bf16* __restrict__ W0,
    const bf16* __restrict__ W1, bf16* __restrict__ out0,
    bf16* __restrict__ outVT, int slab, char* smem)
{
  const int tid  = threadIdx.x;
  const int lane = tid & 63;
  const int w    = tid >> 6;
  const int m    = lane & 15;
  const int g    = lane >> 4;
  const int rowBase = slab * 64;

  char* Xb  = smem;              // [3][16384]  X tile f32
  char* W0b = smem + 49152;      // [3][8192]   W0 tile bf16
  char* W1b = smem + 73728;      // [3][8192]   W1 tile bf16 (KV only)

  const f32x4 vz = {0.f,0.f,0.f,0.f};
  f32x4 accA[4] = {vz, vz, vz, vz};
  f32x4 accB[4] = {vz, vz, vz, vz};   // DCE'd when !KV

  const float* Xbase = X + (size_t)rowBase * NE;

  auto stage = [&](int kt, int buf) {
    // X: 4 instrs/thread (per wave: 16 rows), row-swizzled source, linear LDS
#pragma unroll
    for (int q = 0; q < 4; ++q) {
      int r = (q*4 + w)*4 + (lane >> 4);
      int s = lane & 15;
      const float* src = Xbase + (size_t)r * NE + kt*64 + ((s ^ (r & 15)) * 4);
      void* dst = Xb + buf*16384 + (q*4 + w)*1024;      // wave-uniform base
      gload16(src, dst);
    }
    // W: 2 instrs/thread per matrix
#pragma unroll
    for (int q = 0; q < 2; ++q) {
      int r = (q*4 + w)*8 + (lane >> 3);
      int s = lane & 7;
      size_t soff = (size_t)r * NE + kt*64 + ((s ^ (r & 7)) * 8);
      void* dst0 = W0b + buf*8192 + (q*4 + w)*1024;
      gload16(W0 + soff, dst0);
      if (KV) {
        void* dst1 = W1b + buf*8192 + (q*4 + w)*1024;
        gload16(W1 + soff, dst1);
      }
    }
  };

  auto compute = [&](int buf) {
#pragma unroll
    for (int kk = 0; kk < 2; ++kk) {
      const int arow = 16*w + m;
      const int s0 = 2*(kk*4 + g);
      const char* ab = Xb + buf*16384 + arow*256;
      float4 x0 = *(const float4*)(ab + (( s0      ^ (arow & 15)) * 16));
      float4 x1 = *(const float4*)(ab + (((s0 + 1) ^ (arow & 15)) * 16));
      bf16x8 af = cvt8(x0, x1);
#pragma unroll
      for (int n = 0; n < 4; ++n) {
        const int col = 16*n + m;
        const int ws  = kk*4 + g;
        bf16x8 b0 = *(const bf16x8*)(W0b + buf*8192 + col*128 + ((ws ^ (col & 7)) * 16));
        accA[n] = MFMA16(af, b0, accA[n]);
        if (KV) {
          bf16x8 b1 = *(const bf16x8*)(W1b + buf*8192 + col*128 + ((ws ^ (col & 7)) * 16));
          accB[n] = MFMA16(af, b1, accB[n]);
        }
      }
    }
  };

  stage(0, 0);
  stage(1, 1);
#pragma unroll
  for (int t = 0; t < 16; ++t) {
    if (t < 15) {
      if (KV) asm volatile("s_waitcnt vmcnt(8)" ::: "memory");
      else    asm volatile("s_waitcnt vmcnt(6)" ::: "memory");
    } else {
      asm volatile("s_waitcnt vmcnt(0)" ::: "memory");
    }
    __builtin_amdgcn_s_barrier();           // raw: no compiler drain
    __builtin_amdgcn_sched_barrier(0);
    if (t + 2 < 16) stage(t + 2, (t + 2) % 3);
    __builtin_amdgcn_sched_barrier(0);
    compute(t % 3);
  }

  // C/D: col = lane&15, row = 4*(lane>>4)+i  [m89-verified]
#pragma unroll
  for (int n = 0; n < 4; ++n)
#pragma unroll
    for (int i = 0; i < 4; ++i) {
      int row = rowBase + 16*w + 4*g + i;
      int h   = 16*n + m;
      out0[(size_t)row * HS + h] = (bf16)accA[n][i];
      if (KV)
        outVT[((size_t)(row >> 11) * HS + h) * SEQ + (row & 2047)] =
            (bf16)accB[n][i];
    }
}

__global__ __launch_bounds__(256, 2) void proj_kernel(
    const float* __restrict__ index, const float* __restrict__ memory,
    const bf16* __restrict__ wqb, const bf16* __restrict__ wkb,
    const bf16* __restrict__ wvb, bf16* __restrict__ qb,
    bf16* __restrict__ kb, bf16* __restrict__ vtb)
{
  __shared__ __align__(1024) char smem[98304];   // 96 KB (Q uses 72)
  if (blockIdx.x < 256)
    proj_body<0>(index,  wqb, nullptr, qb, nullptr, blockIdx.x, smem);
  else
    proj_body<1>(memory, wkb, wvb,     kb, vtb, blockIdx.x - 256, smem);
}

// ---- flash attention: swapped-operand softmax (T12), row completed by 2 shuffles ----
// S^T = mfma(K,Q): lane (g,m) holds S[kv=16na+4g+i][q=m] -> a q-row spans the
// 4 g-groups. Row max/sum = in-lane tree + __shfl_xor(16,32). Uniform per-row
// m/l state; PV via O^T = mfma(V^T,P). Wave-split kv, barrier-less main loop.
__global__ __launch_bounds__(128) void attn_kernel(
    const bf16* __restrict__ qb, const bf16* __restrict__ kb,
    const bf16* __restrict__ vtb, float* __restrict__ out)
{
  __shared__ __align__(16) bf16 Ks[2][64][72];    // per-wave K tile [kv][d]
  __shared__ __align__(16) bf16 VTs[2][64][72];   // per-wave V^T tile [d][kv]
  __shared__ __align__(16) bf16 Ps[2][16][72];    // per-wave P [q][kv]

  const int tid  = threadIdx.x;
  const int lane = tid & 63;
  const int w    = tid >> 6;
  const int m    = lane & 15;
  const int g    = lane >> 4;
  const int qt   = 127 - blockIdx.x;   // reversed: longest blocks first
  const int b    = blockIdx.y;
  const int nkv  = (qt >> 2) + 1;
  const int r0   = lane >> 1;
  const int hh   = (lane & 1) * 32;

  // Q fragments, row q = qt*16+m (B-operand; scale pre-baked into Wq)
  bf16x8 qf0 = *(const bf16x8*)(qb + ((size_t)b*SEQ + qt*16 + m)*HS + g*8);
  bf16x8 qf1 = *(const bf16x8*)(qb + ((size_t)b*SEQ + qt*16 + m)*HS + 32 + g*8);

  const f32x4 vz = {0.f,0.f,0.f,0.f};
  f32x4 o_acc[4] = {vz, vz, vz, vz};   // O^T[d=16nd+4g+i][q=m]
  float mrun = -INFINITY, lrun = 0.f;  // row-uniform state for q-row m

  bf16x8 kp[8], vp[8];
  const bf16* kbB = kb  + (size_t)b*SEQ*HS;
  const bf16* vtB = vtb + (size_t)b*HS*SEQ;

  auto loadKV = [&](int j) {
    const bf16* kt_ = kbB + (size_t)j*64*HS;
    const bf16* vt_ = vtB + j*64;
#pragma unroll
    for (int q = 0; q < 4; ++q) {
      kp[q]   = *(const bf16x8*)(kt_ + (size_t)r0*64        + hh + q*8);
      kp[4+q] = *(const bf16x8*)(kt_ + (size_t)(r0+32)*64   + hh + q*8);
      vp[q]   = *(const bf16x8*)(vt_ + (size_t)r0*SEQ       + hh + q*8);
      vp[4+q] = *(const bf16x8*)(vt_ + (size_t)(r0+32)*SEQ  + hh + q*8);
    }
  };
  auto writeKV = [&]() {
#pragma unroll
    for (int q = 0; q < 4; ++q) {
      *(bf16x8*)&Ks[w][r0][hh + q*8]      = kp[q];
      *(bf16x8*)&Ks[w][r0+32][hh + q*8]   = kp[4+q];
      *(bf16x8*)&VTs[w][r0][hh + q*8]     = vp[q];
      *(bf16x8*)&VTs[w][r0+32][hh + q*8]  = vp[4+q];
    }
  };

  int j = w;
  if (j < nkv) {
    loadKV(j);
    writeKV();
    while (true) {
      const int jn = j + 2;
      const bool more = jn < nkv;
      if (more) loadKV(jn);

      // S^T: A = K rows (kv), B = Q (col = q-row m)
      f32x4 s_acc[4];
#pragma unroll
      for (int na = 0; na < 4; ++na) {
        f32x4 z = vz;
        z = MFMA16(*(const bf16x8*)&Ks[w][16*na + m][g*8],      qf0, z);
        z = MFMA16(*(const bf16x8*)&Ks[w][16*na + m][32 + g*8], qf1, z);
        s_acc[na] = z;
      }
      if (j == nkv - 1) {   // causal mask: kv > q
        const int q_ = qt*16 + m;
#pragma unroll
        for (int na = 0; na < 4; ++na)
#pragma unroll
          for (int i = 0; i < 4; ++i)
            if (j*64 + 16*na + 4*g + i > q_) s_acc[na][i] = -INFINITY;
      }

      // row softmax: in-lane tree over this lane's 16 kv + cross-g (2 shuffles)
      float mx = fmaxf(
        fmaxf(fmaxf(fmaxf(s_acc[0][0],s_acc[0][1]),fmaxf(s_acc[0][2],s_acc[0][3])),
              fmaxf(fmaxf(s_acc[1][0],s_acc[1][1]),fmaxf(s_acc[1][2],s_acc[1][3]))),
        fmaxf(fmaxf(fmaxf(s_acc[2][0],s_acc[2][1]),fmaxf(s_acc[2][2],s_acc[2][3])),
              fmaxf(fmaxf(s_acc[3][0],s_acc[3][1]),fmaxf(s_acc[3][2],s_acc[3][3]))));
      mx = fmaxf(mx, __shfl_xor(mx, 16));
      mx = fmaxf(mx, __shfl_xor(mx, 32));   // row max over all 64 kv
      float mnew = fmaxf(mrun, mx);
      float corr = __expf(mrun - mnew);     // finite: row always has live kv
      mrun = mnew;
      float ts = 0.f;
#pragma unroll
      for (int na = 0; na < 4; ++na) {
        bf16x4 pk;
#pragma unroll
        for (int i = 0; i < 4; ++i) {
          float p = __expf(s_acc[na][i] - mnew);
          ts += p;
          pk[i] = (bf16)p;
        }
        *(bf16x4*)&Ps[w][m][16*na + 4*g] = pk;   // P[q=m][kv] (8B packed)
      }
      ts += __shfl_xor(ts, 16);
      ts += __shfl_xor(ts, 32);             // row sum over all 64 kv
      lrun = lrun * corr + ts;
#pragma unroll
      for (int nd = 0; nd < 4; ++nd)
#pragma unroll
        for (int i = 0; i < 4; ++i) o_acc[nd][i] *= corr;

      // O^T += V^T . P : A = V^T rows (d), B = P (col = q-row m)
      bf16x8 pf0 = *(const bf16x8*)&Ps[w][m][g*8];
      bf16x8 pf1 = *(const bf16x8*)&Ps[w][m][32 + g*8];
#pragma unroll
      for (int nd = 0; nd < 4; ++nd) {
        o_acc[nd] = MFMA16(*(const bf16x8*)&VTs[w][16*nd + m][g*8],      pf0, o_acc[nd]);
        o_acc[nd] = MFMA16(*(const bf16x8*)&VTs[w][16*nd + m][32 + g*8], pf1, o_acc[nd]);
      }

      if (!more) break;
      writeKV();               // same-wave DS ordering: safe overwrite
      j = jn;
    }
  }

  // ---- cross-wave merge (O^T form: PO[q][d], pitch 68) ----
  float* PO = (float*)&Ks[w][0][0];    // 16 x 68 f32 = 4.25 KB (fits in 9 KB)
  float* PM = (float*)&VTs[w][0][0];   // m[16], l[16]
#pragma unroll
  for (int nd = 0; nd < 4; ++nd)
    *(f32x4*)&PO[m*68 + 16*nd + 4*g] = o_acc[nd];
  if (g == 0) { PM[m] = mrun; PM[16 + m] = lrun; }
  __syncthreads();

  {
    const int r  = tid >> 3;           // q-row 0..15
    const int c0 = (tid & 7) * 8;
    const float* O0 = (const float*)&Ks[0][0][0];
    const float* O1 = (const float*)&Ks[1][0][0];
    const float* M0 = (const float*)&VTs[0][0][0];
    const float* M1 = (const float*)&VTs[1][0][0];
    float m0 = M0[r], l0 = M0[16 + r];
    float m1 = M1[r], l1 = M1[16 + r];
    float mx = fmaxf(m0, m1);
    float s0 = __expf(m0 - mx), s1 = __expf(m1 - mx);   // exp(-inf)=0
    float inv = 1.f / (s0*l0 + s1*l1);
    float4 x0 = *(const float4*)(O0 + r*68 + c0);
    float4 x1 = *(const float4*)(O0 + r*68 + c0 + 4);
    float4 y0 = *(const float4*)(O1 + r*68 + c0);
    float4 y1 = *(const float4*)(O1 + r*68 + c0 + 4);
    float4 o0, o1;
    o0.x=(x0.x*s0+y0.x*s1)*inv; o0.y=(x0.y*s0+y0.y*s1)*inv;
    o0.z=(x0.z*s0+y0.z*s1)*inv; o0.w=(x0.w*s0+y0.w*s1)*inv;
    o1.x=(x1.x*s0+y1.x*s1)*inv; o1.y=(x1.y*s0+y1.y*s1)*inv;
    o1.z=(x1.z*s0+y1.z*s1)*inv; o1.w=(x1.w*s0+y1.w*s1)*inv;
    float* op = out + ((size_t)b*SEQ + qt*16 + r) * HS + c0;
    *(float4*)(op)     = o0;
    *(float4*)(op + 4) = o1;
  }
}

extern "C" void kernel_launch(void* const* d_in, const int* in_sizes, int n_in,
                              void* d_out, int out_size, void* d_ws, size_t ws_size,
                              hipStream_t stream) {
  (void)in_sizes; (void)n_in; (void)out_size; (void)ws_size;
  const float* index  = (const float*)d_in[0];
  const float* memory = (const float*)d_in[1];
  const float* Wq     = (const float*)d_in[2];
  const float* Wk     = (const float*)d_in[3];
  const float* Wv     = (const float*)d_in[4];
  float* out = (float*)d_out;

  bf16* qb  = (bf16*)d_ws;                          // [NB*SEQ][64]
  bf16* kb  = qb  + (size_t)NB * SEQ * HS;          // [NB*SEQ][64]
  bf16* vtb = kb  + (size_t)NB * SEQ * HS;          // [NB][64][SEQ]
  bf16* wqb = vtb + (size_t)NB * SEQ * HS;          // [64][1024] (pre-scaled)
  bf16* wkb = wqb + (size_t)HS * NE;
  bf16* wvb = wkb + (size_t)HS * NE;

  wcvt_kernel<<<dim3(64), 256, 0, stream>>>(Wq, Wk, Wv, wqb, wkb, wvb);
  proj_kernel<<<dim3(512), 256, 0, stream>>>(index, memory, wqb, wkb, wvb, qb, kb, vtb);
  attn_kernel<<<dim3(128, 8), 128, 0, stream>>>(qb, kb, vtb, out);
}